// Round 1
// 1025.861 us; speedup vs baseline: 1.0747x; 1.0747x over previous
//
#include <hip/hip_runtime.h>
#include <stdint.h>

typedef unsigned short u16;
typedef __attribute__((ext_vector_type(4))) float f32x4;
typedef __attribute__((ext_vector_type(4))) u16 u16x4;
typedef __attribute__((ext_vector_type(8))) u16 u16x8;
typedef __attribute__((ext_vector_type(8))) __bf16 bf16x8;

#define B_ 8
#define S_ 4096
#define D_ 2048
#define O_ 2048
#define M_ 128
#define KTOP_ 256

// ---------- helpers ----------
__device__ __forceinline__ u16 f2bf(float f) {
  unsigned int u = __float_as_uint(f);
  u = (u + 0x7FFFu + ((u >> 16) & 1u)) >> 16;   // RNE; inputs are finite
  return (u16)u;
}

__device__ __forceinline__ void g2l16(const void* g, void* l) {
  __builtin_amdgcn_global_load_lds(
      (const __attribute__((address_space(1))) unsigned int*)g,
      (__attribute__((address_space(3))) unsigned int*)l,
      16, 0, 0);
}

// ---------- 1. fused: x fp32 -> bf16 AND masked prompt partial sums ----------
// grid (D_/1024, S_/64, B_), 256 thr; thread owns 4 consecutive d, 64 rows
__global__ __launch_bounds__(256) void cvt_and_sum(const float* __restrict__ x,
                                                   const int* __restrict__ bnd,
                                                   u16* __restrict__ xb,
                                                   float* __restrict__ sums) {
  const int b = blockIdx.z;
  const int s0 = blockIdx.y * 64;
  const int d = blockIdx.x * 1024 + threadIdx.x * 4;
  const int bclip = min(max(bnd[b], 0), S_ - 1);
  const float* xp = x + (size_t)b * S_ * D_ + (size_t)s0 * D_ + d;
  u16* op = xb + (size_t)b * S_ * D_ + (size_t)s0 * D_ + d;
  // rows s in [s0, s0+64) contribute to the sum iff s <= bclip
  const int smax = min(64, bclip + 1 - s0);
  float a0 = 0.f, a1 = 0.f, a2 = 0.f, a3 = 0.f;
  for (int i = 0; i < 64; ++i) {
    f32x4 v = *(const f32x4*)xp;
    u16x4 r;
    r[0] = f2bf(v[0]); r[1] = f2bf(v[1]); r[2] = f2bf(v[2]); r[3] = f2bf(v[3]);
    *(u16x4*)op = r;
    if (i < smax) { a0 += v[0]; a1 += v[1]; a2 += v[2]; a3 += v[3]; }
    xp += D_; op += D_;
  }
  if (smax > 0) {
    atomicAdd(&sums[b * D_ + d + 0], a0);
    atomicAdd(&sums[b * D_ + d + 1], a1);
    atomicAdd(&sums[b * D_ + d + 2], a2);
    atomicAdd(&sums[b * D_ + d + 3], a3);
  }
}

// ---------- 2. radix-select top-k (exact, JAX tie order), permute -> active ----------
__global__ __launch_bounds__(256) void topk_mask(const float* __restrict__ sums,
                                                 const int* __restrict__ bnd,
                                                 const float* __restrict__ bg_mean,
                                                 const int* __restrict__ perm,
                                                 unsigned char* __restrict__ active) {
  const int b = blockIdx.x;
  __shared__ unsigned int vb[D_];
  __shared__ int hist[256];
  __shared__ int sh_sel, sh_cum;
  const int bclip = min(max(bnd[b], 0), S_ - 1);
  const float denom = (float)(bclip + 1);
  for (int d = threadIdx.x; d < D_; d += 256) {
    float v = fabsf(sums[b * D_ + d] / denom - bg_mean[d]);
    vb[d] = __float_as_uint(v);  // v >= 0 -> uint order == float order
  }
  __syncthreads();
  unsigned int prefix = 0;
  int r = KTOP_;  // remaining rank (1-based from the top)
  for (int byte = 3; byte >= 0; --byte) {
    for (int i = threadIdx.x; i < 256; i += 256) hist[i] = 0;
    __syncthreads();
    const unsigned int shift = byte * 8;
    const unsigned int pmask = (byte == 3) ? 0u : (0xFFFFFFFFu << (shift + 8));
    for (int d = threadIdx.x; d < D_; d += 256) {
      unsigned int v = vb[d];
      if ((v & pmask) == prefix) atomicAdd(&hist[(v >> shift) & 0xFF], 1);
    }
    __syncthreads();
    if (threadIdx.x == 0) {
      int cum = 0, sel = 0;
      for (int v = 255; v >= 0; --v) {
        if (cum + hist[v] >= r) { sel = v; break; }
        cum += hist[v];
      }
      sh_sel = sel; sh_cum = cum;
    }
    __syncthreads();
    prefix |= ((unsigned int)sh_sel) << shift;
    r -= sh_cum;
    __syncthreads();
  }
  const unsigned int T = prefix;  // exact K-th largest; r = # ties to take
  for (int d = threadIdx.x; d < D_; d += 256)
    if (vb[d] > T) active[b * D_ + perm[d]] = 1;
  if (threadIdx.x == 0) {
    int need = r;
    for (int d = 0; d < D_ && need > 0; ++d)
      if (vb[d] == T) { active[b * D_ + perm[d]] = 1; --need; }
  }
}

// ---------- 3. overlap with saved masks, argmax, build final mask ----------
__global__ __launch_bounds__(128) void select_mask(const unsigned char* __restrict__ active,
                                                   const unsigned char* __restrict__ saved,
                                                   unsigned char* __restrict__ final_mask) {
  const int b = blockIdx.x;
  const int m = threadIdx.x;
  __shared__ __align__(16) unsigned char act[D_];
  __shared__ int cnts[M_];
  __shared__ int sh_best, sh_rel;
  for (int d = m; d < D_; d += 128) act[d] = active[b * D_ + d];
  __syncthreads();
  const unsigned int* sp = (const unsigned int*)(saved + (size_t)m * D_);
  const unsigned int* ap = (const unsigned int*)act;
  int c = 0;
  for (int i = 0; i < D_ / 4; ++i) c += __popc(sp[i] & ap[i]);  // bytes are 0/1
  cnts[m] = c;
  __syncthreads();
  if (m == 0) {
    int best = cnts[0], bi = 0;
    for (int i = 1; i < M_; ++i)
      if (cnts[i] > best) { best = cnts[i]; bi = i; }
    sh_best = bi;
    sh_rel = (best >= 77) ? 1 : 0;  // best/256 >= 0.3f exact integer form
  }
  __syncthreads();
  const int bi = sh_best, rel = sh_rel;
  for (int d = m; d < D_; d += 128)
    final_mask[b * D_ + d] = rel ? saved[(size_t)bi * D_ + d] : 0;
}

// ---------- 4. W_eff[b] = W + mask[b] * W_new  -> bf16 ----------
__global__ __launch_bounds__(256) void build_weff(const float* __restrict__ w,
                                                  const float* __restrict__ nw,
                                                  const unsigned char* __restrict__ fmask,
                                                  u16* __restrict__ weff) {
  int idx = blockIdx.x * 256 + threadIdx.x;
  int bb = idx >> 19;
  int rem = (idx & 524287) << 3;
  int d = rem & (D_ - 1);
  f32x4 w0 = *(const f32x4*)(w + rem);
  f32x4 w1 = *(const f32x4*)(w + rem + 4);
  f32x4 n0 = *(const f32x4*)(nw + rem);
  f32x4 n1 = *(const f32x4*)(nw + rem + 4);
  const unsigned char* mp = fmask + bb * D_ + d;
  u16x8 r;
#pragma unroll
  for (int i = 0; i < 4; ++i) r[i] = f2bf(w0[i] + (mp[i] ? n0[i] : 0.f));
#pragma unroll
  for (int i = 0; i < 4; ++i) r[4 + i] = f2bf(w1[i] + (mp[4 + i] ? n1[i] : 0.f));
  *(u16x8*)(weff + ((size_t)bb << 22) + rem) = r;
}

// ---------- 5. batched bf16 GEMM: out[b] = Xb[b] @ Weff[b]^T + bias ----------
// 256x256 tile, BK=64, 8 waves (2Mx4N), 512 thr, 128 KiB LDS double-buffer.
// 4-phase-per-K-step schedule (8-phase template, T2+T3+T4+T5):
//   LDS layout: [buf][256][64] bf16, chunk-XOR swizzle c_lin = c ^ (row&7)
//   (16B chunks). global_load_lds writes LINEAR dest (base+tid*16); the
//   swizzle is applied by pre-swizzling the GLOBAL source address and using
//   the same XOR on ds_read (involution; rule #21).
// Hazard schedule (why stages never race reads):
//   wave (wm,wn) only ever reads A-half wm and B-half (wn>>1).
//   A-frag reads finish by phase-2's closing barrier; B-frag reads by
//   phase-3's. So: ph1/ph2 stage B-lo/hi(j+1) into the OTHER buffer (its
//   B reads finished last K-step), ph3/ph4 stage A-lo/hi(j+2) into the
//   CURRENT buffer's A region (freed at ph2 barrier). At each K-step
//   boundary vmcnt(4) leaves exactly A-lo/hi(j+2) (4 loads) in flight --
//   never drains to 0 in steady state.
#define MFMA16(a, b, c) __builtin_amdgcn_mfma_f32_16x16x32_bf16((a), (b), (c), 0, 0, 0)

__global__ __launch_bounds__(512) void gemm256(const u16* __restrict__ X,
                                               const u16* __restrict__ W,
                                               const float* __restrict__ bias,
                                               float* __restrict__ out) {
  __shared__ __align__(16) u16 ldsA[2][256][64];   // 64 KiB
  __shared__ __align__(16) u16 ldsB[2][256][64];   // 64 KiB
  const unsigned int gid = blockIdx.x;
  const int b = gid & 7;            // batch per XCD (round-robin dispatch)
  const int t = gid >> 3;           // 0..127 within batch
  const int nt = t & 7;             // 8 col-tiles
  const int mt = t >> 3;            // 16 row-tiles
  const int tid = threadIdx.x;
  const int wave = tid >> 6, lane = tid & 63;
  const int wm = wave >> 2, wn = wave & 3;          // 2 x 4 wave grid
  const int q = lane >> 4, lm = lane & 15;
  const int l7 = lm & 7;
  const int cA0 = (q ^ l7) << 3;                    // kk=0 swizzled chunk (elems); kk=1 = cA0^32
  const int tRow = tid >> 3;                        // staging row 0..63
  const int cSw = ((tid & 7) ^ (tRow & 7)) << 3;    // pre-swizzled global chunk (elems)

  const u16* Ab = X + (size_t)b * S_ * D_ + (size_t)(mt * 256) * D_;
  const u16* Bb = W + (size_t)b * O_ * D_ + (size_t)(nt * 256) * D_;

#define STAGE_A(p, kt, h) do {                                              \
    const u16* s_ = Ab + (size_t)((h) * 128 + tRow) * D_ + (kt) * 64 + cSw; \
    g2l16(s_, &ldsA[p][(h) * 128][0] + tid * 8);                            \
    g2l16(s_ + (size_t)64 * D_, &ldsA[p][(h) * 128 + 64][0] + tid * 8);     \
  } while (0)
#define STAGE_B(p, kt, h) do {                                              \
    const u16* s_ = Bb + (size_t)((h) * 128 + tRow) * D_ + (kt) * 64 + cSw; \
    g2l16(s_, &ldsB[p][(h) * 128][0] + tid * 8);                            \
    g2l16(s_ + (size_t)64 * D_, &ldsB[p][(h) * 128 + 64][0] + tid * 8);     \
  } while (0)

  f32x4 acc[8][4] = {};

  // prologue: K-step 0 fully + A-halves of K-step 1 (12 loads/thread)
  STAGE_A(0, 0, 0); STAGE_A(0, 0, 1);
  STAGE_B(0, 0, 0); STAGE_B(0, 0, 1);
  STAGE_A(1, 1, 0); STAGE_A(1, 1, 1);
  asm volatile("s_waitcnt vmcnt(4)" ::: "memory");  // K-step 0 landed; A(1) in flight
  __builtin_amdgcn_s_barrier();

  const int NK = D_ / 64;  // 32
  for (int j = 0; j < NK; ++j) {
    const int p = j & 1;
    const u16* la = &ldsA[p][0][0];
    const u16* lb = &ldsB[p][0][0];
    bf16x8 af0[4][2], af4[4][2], bf01[2][2], bf23[2][2];

    // ---- phase 1: read A0-3 + B0-1 (12 ds_read), stage B-lo(j+1), MFMA Q0 ----
#pragma unroll
    for (int i = 0; i < 4; ++i) {
      const u16* rp = la + (wm * 128 + i * 16 + lm) * 64;
      af0[i][0] = *(const bf16x8*)(rp + cA0);
      af0[i][1] = *(const bf16x8*)(rp + (cA0 ^ 32));
    }
#pragma unroll
    for (int n = 0; n < 2; ++n) {
      const u16* rp = lb + (wn * 64 + n * 16 + lm) * 64;
      bf01[n][0] = *(const bf16x8*)(rp + cA0);
      bf01[n][1] = *(const bf16x8*)(rp + (cA0 ^ 32));
    }
    if (j + 1 < NK) STAGE_B(p ^ 1, j + 1, 0);
    __builtin_amdgcn_s_barrier();
    __builtin_amdgcn_s_setprio(1);
#pragma unroll
    for (int i = 0; i < 4; ++i)
#pragma unroll
      for (int n = 0; n < 2; ++n) {
        acc[i][n] = MFMA16(af0[i][0], bf01[n][0], acc[i][n]);
        acc[i][n] = MFMA16(af0[i][1], bf01[n][1], acc[i][n]);
      }
    __builtin_amdgcn_s_setprio(0);
    __builtin_amdgcn_s_barrier();

    // ---- phase 2: read A4-7 (8 ds_read), stage B-hi(j+1), MFMA Q1 ----
#pragma unroll
    for (int i = 0; i < 4; ++i) {
      const u16* rp = la + (wm * 128 + 64 + i * 16 + lm) * 64;
      af4[i][0] = *(const bf16x8*)(rp + cA0);
      af4[i][1] = *(const bf16x8*)(rp + (cA0 ^ 32));
    }
    if (j + 1 < NK) STAGE_B(p ^ 1, j + 1, 1);
    __builtin_amdgcn_s_barrier();
    __builtin_amdgcn_s_setprio(1);
#pragma unroll
    for (int i = 0; i < 4; ++i)
#pragma unroll
      for (int n = 0; n < 2; ++n) {
        acc[4 + i][n] = MFMA16(af4[i][0], bf01[n][0], acc[4 + i][n]);
        acc[4 + i][n] = MFMA16(af4[i][1], bf01[n][1], acc[4 + i][n]);
      }
    __builtin_amdgcn_s_setprio(0);
    __builtin_amdgcn_s_barrier();   // <- all A reads of buf p done here

    // ---- phase 3: read B2-3 (4 ds_read), stage A-lo(j+2) into buf p, MFMA Q2 ----
#pragma unroll
    for (int n = 0; n < 2; ++n) {
      const u16* rp = lb + (wn * 64 + (2 + n) * 16 + lm) * 64;
      bf23[n][0] = *(const bf16x8*)(rp + cA0);
      bf23[n][1] = *(const bf16x8*)(rp + (cA0 ^ 32));
    }
    if (j + 2 < NK) STAGE_A(p, j + 2, 0);
    __builtin_amdgcn_s_barrier();
    __builtin_amdgcn_s_setprio(1);
#pragma unroll
    for (int i = 0; i < 4; ++i)
#pragma unroll
      for (int n = 0; n < 2; ++n) {
        acc[4 + i][2 + n] = MFMA16(af4[i][0], bf23[n][0], acc[4 + i][2 + n]);
        acc[4 + i][2 + n] = MFMA16(af4[i][1], bf23[n][1], acc[4 + i][2 + n]);
      }
    __builtin_amdgcn_s_setprio(0);
    __builtin_amdgcn_s_barrier();   // <- all B reads of buf p done here

    // ---- phase 4: stage A-hi(j+2), counted vmcnt at K-step boundary, MFMA Q3 ----
    if (j + 2 < NK) STAGE_A(p, j + 2, 1);
    if (j < NK - 2) asm volatile("s_waitcnt vmcnt(4)" ::: "memory");
    else            asm volatile("s_waitcnt vmcnt(0)" ::: "memory");
    __builtin_amdgcn_s_barrier();
    __builtin_amdgcn_s_setprio(1);
#pragma unroll
    for (int i = 0; i < 4; ++i)
#pragma unroll
      for (int n = 0; n < 2; ++n) {
        acc[i][2 + n] = MFMA16(af0[i][0], bf23[n][0], acc[i][2 + n]);
        acc[i][2 + n] = MFMA16(af0[i][1], bf23[n][1], acc[i][2 + n]);
      }
    __builtin_amdgcn_s_setprio(0);
    __builtin_amdgcn_s_barrier();
  }
#undef STAGE_A
#undef STAGE_B

  // epilogue: C/D layout col=lane&15, row=q*4+reg
  const int colbase = nt * 256 + wn * 64 + lm;
  const int rowbase = mt * 256 + wm * 128 + q * 4;
  float bv[4];
#pragma unroll
  for (int n = 0; n < 4; ++n) bv[n] = bias[colbase + n * 16];
  float* outb = out + (size_t)b * S_ * O_;
#pragma unroll
  for (int i = 0; i < 8; ++i) {
#pragma unroll
    for (int rr = 0; rr < 4; ++rr) {
      float* op = outb + (size_t)(rowbase + i * 16 + rr) * O_ + colbase;
#pragma unroll
      for (int n = 0; n < 4; ++n) op[n * 16] = acc[i][n][rr] + bv[n];
    }
  }
}

// ---------- launch ----------
extern "C" void kernel_launch(void* const* d_in, const int* in_sizes, int n_in,
                              void* d_out, int out_size, void* d_ws, size_t ws_size,
                              hipStream_t stream) {
  const float* x          = (const float*)d_in[0];
  const int* boundaries   = (const int*)d_in[1];
  const float* weight     = (const float*)d_in[2];
  const float* bias       = (const float*)d_in[3];
  const float* new_weight = (const float*)d_in[4];
  const int* perm         = (const int*)d_in[5];
  const unsigned char* saved = (const unsigned char*)d_in[6];
  const float* bg_mean    = (const float*)d_in[7];
  float* out = (float*)d_out;

  char* ws = (char*)d_ws;
  const size_t off_xb   = 0;                                   // 128 MB
  const size_t off_weff = off_xb + (size_t)B_ * S_ * D_ * 2;   // 64 MB
  const size_t off_sums = off_weff + (size_t)B_ * O_ * D_ * 2; // 64 KB
  const size_t off_act  = off_sums + (size_t)B_ * D_ * 4;      // 16 KB
  const size_t off_fin  = off_act + (size_t)B_ * D_;           // 16 KB

  u16* xb   = (u16*)(ws + off_xb);
  u16* weff = (u16*)(ws + off_weff);
  float* sums = (float*)(ws + off_sums);
  unsigned char* act = (unsigned char*)(ws + off_act);
  unsigned char* fin = (unsigned char*)(ws + off_fin);

  hipMemsetAsync(ws + off_sums, 0, (size_t)B_ * D_ * 4 + (size_t)B_ * D_, stream);

  cvt_and_sum<<<dim3(D_ / 1024, S_ / 64, B_), 256, 0, stream>>>(x, boundaries, xb, sums);
  topk_mask<<<B_, 256, 0, stream>>>(sums, boundaries, bg_mean, perm, act);
  select_mask<<<B_, 128, 0, stream>>>(act, saved, fin);
  build_weff<<<(B_ * O_ * D_ / 8) / 256, 256, 0, stream>>>(weight, new_weight, fin, weff);
  gemm256<<<B_ * 128, 512, 0, stream>>>(xb, weff, bias, out);
}

// Round 2
// 953.958 us; speedup vs baseline: 1.1557x; 1.0754x over previous
//
#include <hip/hip_runtime.h>
#include <stdint.h>

typedef unsigned short u16;
typedef __attribute__((ext_vector_type(4))) float f32x4;
typedef __attribute__((ext_vector_type(4))) u16 u16x4;
typedef __attribute__((ext_vector_type(8))) u16 u16x8;
typedef __attribute__((ext_vector_type(8))) __bf16 bf16x8;

#define B_ 8
#define S_ 4096
#define D_ 2048
#define O_ 2048
#define M_ 128
#define KTOP_ 256

// ---------- helpers ----------
__device__ __forceinline__ u16 f2bf(float f) {
  unsigned int u = __float_as_uint(f);
  u = (u + 0x7FFFu + ((u >> 16) & 1u)) >> 16;   // RNE; inputs are finite
  return (u16)u;
}

__device__ __forceinline__ void g2l16(const void* g, void* l) {
  __builtin_amdgcn_global_load_lds(
      (const __attribute__((address_space(1))) unsigned int*)g,
      (__attribute__((address_space(3))) unsigned int*)l,
      16, 0, 0);
}

// ---------- 1. fused: x fp32 -> bf16 AND masked prompt partial sums ----------
// grid (D_/1024, S_/64, B_), 256 thr; thread owns 4 consecutive d, 64 rows
__global__ __launch_bounds__(256) void cvt_and_sum(const float* __restrict__ x,
                                                   const int* __restrict__ bnd,
                                                   u16* __restrict__ xb,
                                                   float* __restrict__ sums) {
  const int b = blockIdx.z;
  const int s0 = blockIdx.y * 64;
  const int d = blockIdx.x * 1024 + threadIdx.x * 4;
  const int bclip = min(max(bnd[b], 0), S_ - 1);
  const float* xp = x + (size_t)b * S_ * D_ + (size_t)s0 * D_ + d;
  u16* op = xb + (size_t)b * S_ * D_ + (size_t)s0 * D_ + d;
  // rows s in [s0, s0+64) contribute to the sum iff s <= bclip
  const int smax = min(64, bclip + 1 - s0);
  float a0 = 0.f, a1 = 0.f, a2 = 0.f, a3 = 0.f;
  for (int i = 0; i < 64; ++i) {
    f32x4 v = *(const f32x4*)xp;
    u16x4 r;
    r[0] = f2bf(v[0]); r[1] = f2bf(v[1]); r[2] = f2bf(v[2]); r[3] = f2bf(v[3]);
    *(u16x4*)op = r;
    if (i < smax) { a0 += v[0]; a1 += v[1]; a2 += v[2]; a3 += v[3]; }
    xp += D_; op += D_;
  }
  if (smax > 0) {
    atomicAdd(&sums[b * D_ + d + 0], a0);
    atomicAdd(&sums[b * D_ + d + 1], a1);
    atomicAdd(&sums[b * D_ + d + 2], a2);
    atomicAdd(&sums[b * D_ + d + 3], a3);
  }
}

// ---------- 2. radix-select top-k (exact, JAX tie order), permute -> active ----------
__global__ __launch_bounds__(256) void topk_mask(const float* __restrict__ sums,
                                                 const int* __restrict__ bnd,
                                                 const float* __restrict__ bg_mean,
                                                 const int* __restrict__ perm,
                                                 unsigned char* __restrict__ active) {
  const int b = blockIdx.x;
  __shared__ unsigned int vb[D_];
  __shared__ int hist[256];
  __shared__ int sh_sel, sh_cum;
  const int bclip = min(max(bnd[b], 0), S_ - 1);
  const float denom = (float)(bclip + 1);
  for (int d = threadIdx.x; d < D_; d += 256) {
    float v = fabsf(sums[b * D_ + d] / denom - bg_mean[d]);
    vb[d] = __float_as_uint(v);  // v >= 0 -> uint order == float order
  }
  __syncthreads();
  unsigned int prefix = 0;
  int r = KTOP_;  // remaining rank (1-based from the top)
  for (int byte = 3; byte >= 0; --byte) {
    for (int i = threadIdx.x; i < 256; i += 256) hist[i] = 0;
    __syncthreads();
    const unsigned int shift = byte * 8;
    const unsigned int pmask = (byte == 3) ? 0u : (0xFFFFFFFFu << (shift + 8));
    for (int d = threadIdx.x; d < D_; d += 256) {
      unsigned int v = vb[d];
      if ((v & pmask) == prefix) atomicAdd(&hist[(v >> shift) & 0xFF], 1);
    }
    __syncthreads();
    if (threadIdx.x == 0) {
      int cum = 0, sel = 0;
      for (int v = 255; v >= 0; --v) {
        if (cum + hist[v] >= r) { sel = v; break; }
        cum += hist[v];
      }
      sh_sel = sel; sh_cum = cum;
    }
    __syncthreads();
    prefix |= ((unsigned int)sh_sel) << shift;
    r -= sh_cum;
    __syncthreads();
  }
  const unsigned int T = prefix;  // exact K-th largest; r = # ties to take
  for (int d = threadIdx.x; d < D_; d += 256)
    if (vb[d] > T) active[b * D_ + perm[d]] = 1;
  if (threadIdx.x == 0) {
    int need = r;
    for (int d = 0; d < D_ && need > 0; ++d)
      if (vb[d] == T) { active[b * D_ + perm[d]] = 1; --need; }
  }
}

// ---------- 3. overlap with saved masks, argmax, build final mask ----------
__global__ __launch_bounds__(128) void select_mask(const unsigned char* __restrict__ active,
                                                   const unsigned char* __restrict__ saved,
                                                   unsigned char* __restrict__ final_mask) {
  const int b = blockIdx.x;
  const int m = threadIdx.x;
  __shared__ __align__(16) unsigned char act[D_];
  __shared__ int cnts[M_];
  __shared__ int sh_best, sh_rel;
  for (int d = m; d < D_; d += 128) act[d] = active[b * D_ + d];
  __syncthreads();
  const unsigned int* sp = (const unsigned int*)(saved + (size_t)m * D_);
  const unsigned int* ap = (const unsigned int*)act;
  int c = 0;
  for (int i = 0; i < D_ / 4; ++i) c += __popc(sp[i] & ap[i]);  // bytes are 0/1
  cnts[m] = c;
  __syncthreads();
  if (m == 0) {
    int best = cnts[0], bi = 0;
    for (int i = 1; i < M_; ++i)
      if (cnts[i] > best) { best = cnts[i]; bi = i; }
    sh_best = bi;
    sh_rel = (best >= 77) ? 1 : 0;  // best/256 >= 0.3f exact integer form
  }
  __syncthreads();
  const int bi = sh_best, rel = sh_rel;
  for (int d = m; d < D_; d += 128)
    final_mask[b * D_ + d] = rel ? saved[(size_t)bi * D_ + d] : 0;
}

// ---------- 4. W_eff[b] = W + mask[b] * W_new  -> bf16 ----------
__global__ __launch_bounds__(256) void build_weff(const float* __restrict__ w,
                                                  const float* __restrict__ nw,
                                                  const unsigned char* __restrict__ fmask,
                                                  u16* __restrict__ weff) {
  int idx = blockIdx.x * 256 + threadIdx.x;
  int bb = idx >> 19;
  int rem = (idx & 524287) << 3;
  int d = rem & (D_ - 1);
  f32x4 w0 = *(const f32x4*)(w + rem);
  f32x4 w1 = *(const f32x4*)(w + rem + 4);
  f32x4 n0 = *(const f32x4*)(nw + rem);
  f32x4 n1 = *(const f32x4*)(nw + rem + 4);
  const unsigned char* mp = fmask + bb * D_ + d;
  u16x8 r;
#pragma unroll
  for (int i = 0; i < 4; ++i) r[i] = f2bf(w0[i] + (mp[i] ? n0[i] : 0.f));
#pragma unroll
  for (int i = 0; i < 4; ++i) r[4 + i] = f2bf(w1[i] + (mp[4 + i] ? n1[i] : 0.f));
  *(u16x8*)(weff + ((size_t)bb << 22) + rem) = r;
}

// ---------- 5. batched bf16 GEMM: out[b] = Xb[b] @ Weff[b]^T + bias ----------
// 256x256 tile, BK=64, 8 waves (2Mx4N), 512 thr, 128 KiB LDS double-buffer.
// 2-BARRIER-per-K-step schedule (drift-pipelined):
//   All 24 fragment ds_reads issue in the first half of the step; the
//   compiler's per-use counted lgkmcnt lets af4/bf23 land UNDER Q0/Q1's
//   MFMA. Only two barriers are needed per step:
//     barrier #1 (after Q1): DS ops complete in-order per wave, so every
//       wave's A-region (and bf01) reads are retired before its Q1 MFMAs
//       issue -> after this barrier A[p] may be restaged with A(j+2).
//     barrier #2 (boundary, after per-wave vmcnt(4)): outstanding loads
//       oldest->newest are A(j+1)x4, B(j+1)x4, A(j+2)x4; vmcnt(4) waits
//       for the oldest 8 = exactly what step j+1 reads. Never drains to 0
//       in steady state. Barrier AFTER the vmcnt makes "my loads landed"
//       hold for ALL waves' loads.
//   Between barriers waves drift, so one wave's LDS reads overlap another
//   wave's MFMA (m114 mechanism); ~32 MFMA/barrier matches AITER's ratio.
//   LDS chunk-XOR swizzle (c ^= row&7 on 16B chunks) unchanged: staging
//   keeps LINEAR LDS dest + inverse-swizzled GLOBAL source; reads apply
//   the same XOR (involution, rule #21). Bank conflicts measured 0.
#define MFMA16(a, b, c) __builtin_amdgcn_mfma_f32_16x16x32_bf16((a), (b), (c), 0, 0, 0)

__global__ __launch_bounds__(512) void gemm256(const u16* __restrict__ X,
                                               const u16* __restrict__ W,
                                               const float* __restrict__ bias,
                                               float* __restrict__ out) {
  __shared__ __align__(16) u16 ldsA[2][256][64];   // 64 KiB
  __shared__ __align__(16) u16 ldsB[2][256][64];   // 64 KiB
  const unsigned int gid = blockIdx.x;
  const int b = gid & 7;            // batch per XCD (round-robin dispatch)
  const int t = gid >> 3;           // 0..127 within batch
  const int nt = t & 7;             // 8 col-tiles
  const int mt = t >> 3;            // 16 row-tiles
  const int tid = threadIdx.x;
  const int wave = tid >> 6, lane = tid & 63;
  const int wm = wave >> 2, wn = wave & 3;          // 2 x 4 wave grid
  const int q = lane >> 4, lm = lane & 15;
  const int l7 = lm & 7;
  const int cA0 = (q ^ l7) << 3;                    // kk=0 swizzled chunk (elems); kk=1 = cA0^32
  const int tRow = tid >> 3;                        // staging row 0..63
  const int cSw = ((tid & 7) ^ (tRow & 7)) << 3;    // pre-swizzled global chunk (elems)

  const u16* Ab = X + (size_t)b * S_ * D_ + (size_t)(mt * 256) * D_;
  const u16* Bb = W + (size_t)b * O_ * D_ + (size_t)(nt * 256) * D_;

#define STAGE_A(p, kt, h) do {                                              \
    const u16* s_ = Ab + (size_t)((h) * 128 + tRow) * D_ + (kt) * 64 + cSw; \
    g2l16(s_, &ldsA[p][(h) * 128][0] + tid * 8);                            \
    g2l16(s_ + (size_t)64 * D_, &ldsA[p][(h) * 128 + 64][0] + tid * 8);     \
  } while (0)
#define STAGE_B(p, kt, h) do {                                              \
    const u16* s_ = Bb + (size_t)((h) * 128 + tRow) * D_ + (kt) * 64 + cSw; \
    g2l16(s_, &ldsB[p][(h) * 128][0] + tid * 8);                            \
    g2l16(s_ + (size_t)64 * D_, &ldsB[p][(h) * 128 + 64][0] + tid * 8);     \
  } while (0)

  f32x4 acc[8][4] = {};

  // prologue: K-step 0 fully + A-halves of K-step 1 (12 loads/thread)
  STAGE_A(0, 0, 0); STAGE_A(0, 0, 1);
  STAGE_B(0, 0, 0); STAGE_B(0, 0, 1);
  STAGE_A(1, 1, 0); STAGE_A(1, 1, 1);
  asm volatile("s_waitcnt vmcnt(4)" ::: "memory");  // K-step 0 landed; A(1) in flight
  __builtin_amdgcn_s_barrier();
  asm volatile("" ::: "memory");

  const int NK = D_ / 64;  // 32
  for (int j = 0; j < NK; ++j) {
    const int p = j & 1;
    const u16* la = &ldsA[p][0][0];
    const u16* lb = &ldsB[p][0][0];
    bf16x8 af0[4][2], af4[4][2], bf01[2][2], bf23[2][2];

    // ---- read batch 1: af0 (8) + bf01 (4) + af4 (8); in-order DS completion
    //      means Q0's operands land first, af4 lands under Q0's MFMA ----
#pragma unroll
    for (int i = 0; i < 4; ++i) {
      const u16* rp = la + (wm * 128 + i * 16 + lm) * 64;
      af0[i][0] = *(const bf16x8*)(rp + cA0);
      af0[i][1] = *(const bf16x8*)(rp + (cA0 ^ 32));
    }
#pragma unroll
    for (int n = 0; n < 2; ++n) {
      const u16* rp = lb + (wn * 64 + n * 16 + lm) * 64;
      bf01[n][0] = *(const bf16x8*)(rp + cA0);
      bf01[n][1] = *(const bf16x8*)(rp + (cA0 ^ 32));
    }
#pragma unroll
    for (int i = 0; i < 4; ++i) {
      const u16* rp = la + (wm * 128 + 64 + i * 16 + lm) * 64;
      af4[i][0] = *(const bf16x8*)(rp + cA0);
      af4[i][1] = *(const bf16x8*)(rp + (cA0 ^ 32));
    }
    if (j + 1 < NK) STAGE_B(p ^ 1, j + 1, 0);   // B-lo(j+1): B[p^1] free since boundary(j-1)

    // ---- Q0: acc[0..3][0..1] += af0 x bf01 ----
    __builtin_amdgcn_s_setprio(1);
#pragma unroll
    for (int i = 0; i < 4; ++i)
#pragma unroll
      for (int n = 0; n < 2; ++n) {
        acc[i][n] = MFMA16(af0[i][0], bf01[n][0], acc[i][n]);
        acc[i][n] = MFMA16(af0[i][1], bf01[n][1], acc[i][n]);
      }
    __builtin_amdgcn_s_setprio(0);

    if (j + 1 < NK) STAGE_B(p ^ 1, j + 1, 1);   // B-hi(j+1)
    // ---- read batch 2: bf23 (4) — lands under Q1's MFMA ----
#pragma unroll
    for (int n = 0; n < 2; ++n) {
      const u16* rp = lb + (wn * 64 + (2 + n) * 16 + lm) * 64;
      bf23[n][0] = *(const bf16x8*)(rp + cA0);
      bf23[n][1] = *(const bf16x8*)(rp + (cA0 ^ 32));
    }

    // ---- Q1: acc[4..7][0..1] += af4 x bf01 ----
    __builtin_amdgcn_s_setprio(1);
#pragma unroll
    for (int i = 0; i < 4; ++i)
#pragma unroll
      for (int n = 0; n < 2; ++n) {
        acc[4 + i][n] = MFMA16(af4[i][0], bf01[n][0], acc[4 + i][n]);
        acc[4 + i][n] = MFMA16(af4[i][1], bf01[n][1], acc[4 + i][n]);
      }
    __builtin_amdgcn_s_setprio(0);

    // ---- barrier #1: every wave's A-region reads retired (used by Q1) ----
    asm volatile("" ::: "memory");
    __builtin_amdgcn_s_barrier();
    asm volatile("" ::: "memory");

    if (j + 2 < NK) STAGE_A(p, j + 2, 0);       // A-lo(j+2) into freed A[p]

    // ---- Q2: acc[4..7][2..3] += af4 x bf23 (registers only) ----
    __builtin_amdgcn_s_setprio(1);
#pragma unroll
    for (int i = 0; i < 4; ++i)
#pragma unroll
      for (int n = 0; n < 2; ++n) {
        acc[4 + i][2 + n] = MFMA16(af4[i][0], bf23[n][0], acc[4 + i][2 + n]);
        acc[4 + i][2 + n] = MFMA16(af4[i][1], bf23[n][1], acc[4 + i][2 + n]);
      }
    __builtin_amdgcn_s_setprio(0);

    if (j + 2 < NK) STAGE_A(p, j + 2, 1);       // A-hi(j+2)

    // ---- Q3: acc[0..3][2..3] += af0 x bf23 (registers only) ----
    __builtin_amdgcn_s_setprio(1);
#pragma unroll
    for (int i = 0; i < 4; ++i)
#pragma unroll
      for (int n = 0; n < 2; ++n) {
        acc[i][2 + n] = MFMA16(af0[i][0], bf23[n][0], acc[i][2 + n]);
        acc[i][2 + n] = MFMA16(af0[i][1], bf23[n][1], acc[i][2 + n]);
      }
    __builtin_amdgcn_s_setprio(0);

    // ---- barrier #2 (boundary): counted vmcnt, never 0 in steady state ----
    if (j < NK - 2) asm volatile("s_waitcnt vmcnt(4)" ::: "memory");
    else            asm volatile("s_waitcnt vmcnt(0)" ::: "memory");
    __builtin_amdgcn_s_barrier();
    asm volatile("" ::: "memory");
  }
#undef STAGE_A
#undef STAGE_B

  // epilogue: C/D layout col=lane&15, row=q*4+reg
  const int colbase = nt * 256 + wn * 64 + lm;
  const int rowbase = mt * 256 + wm * 128 + q * 4;
  float bv[4];
#pragma unroll
  for (int n = 0; n < 4; ++n) bv[n] = bias[colbase + n * 16];
  float* outb = out + (size_t)b * S_ * O_;
#pragma unroll
  for (int i = 0; i < 8; ++i) {
#pragma unroll
    for (int rr = 0; rr < 4; ++rr) {
      float* op = outb + (size_t)(rowbase + i * 16 + rr) * O_ + colbase;
#pragma unroll
      for (int n = 0; n < 4; ++n) op[n * 16] = acc[i][n][rr] + bv[n];
    }
  }
}

// ---------- launch ----------
extern "C" void kernel_launch(void* const* d_in, const int* in_sizes, int n_in,
                              void* d_out, int out_size, void* d_ws, size_t ws_size,
                              hipStream_t stream) {
  const float* x          = (const float*)d_in[0];
  const int* boundaries   = (const int*)d_in[1];
  const float* weight     = (const float*)d_in[2];
  const float* bias       = (const float*)d_in[3];
  const float* new_weight = (const float*)d_in[4];
  const int* perm         = (const int*)d_in[5];
  const unsigned char* saved = (const unsigned char*)d_in[6];
  const float* bg_mean    = (const float*)d_in[7];
  float* out = (float*)d_out;

  char* ws = (char*)d_ws;
  const size_t off_xb   = 0;                                   // 128 MB
  const size_t off_weff = off_xb + (size_t)B_ * S_ * D_ * 2;   // 64 MB
  const size_t off_sums = off_weff + (size_t)B_ * O_ * D_ * 2; // 64 KB
  const size_t off_act  = off_sums + (size_t)B_ * D_ * 4;      // 16 KB
  const size_t off_fin  = off_act + (size_t)B_ * D_;           // 16 KB

  u16* xb   = (u16*)(ws + off_xb);
  u16* weff = (u16*)(ws + off_weff);
  float* sums = (float*)(ws + off_sums);
  unsigned char* act = (unsigned char*)(ws + off_act);
  unsigned char* fin = (unsigned char*)(ws + off_fin);

  hipMemsetAsync(ws + off_sums, 0, (size_t)B_ * D_ * 4 + (size_t)B_ * D_, stream);

  cvt_and_sum<<<dim3(D_ / 1024, S_ / 64, B_), 256, 0, stream>>>(x, boundaries, xb, sums);
  topk_mask<<<B_, 256, 0, stream>>>(sums, boundaries, bg_mean, perm, act);
  select_mask<<<B_, 128, 0, stream>>>(act, saved, fin);
  build_weff<<<(B_ * O_ * D_ / 8) / 256, 256, 0, stream>>>(weight, new_weight, fin, weff);
  gemm256<<<B_ * 128, 512, 0, stream>>>(xb, weff, bias, out);
}